// Round 3
// baseline (2282.157 us; speedup 1.0000x reference)
//
#include <hip/hip_runtime.h>
#include <math.h>

#define HD 128
#define NBR 8
#define LSTEPS 64
#define TILE_B 32
#define HT_PAD 36     // 144B rows: float4-aligned; GEMM h-reads are wave-uniform broadcasts
#define PART_PAD 132  // 4-way on write/read: ~1.6x on a handful of ds ops, negligible

// workspace layout (floats)
#define WPT_OFF   0        // w_hh permuted-transposed: [k][4*hh+q] = w_hh[q*128+hh][k]   (128*512)
#define WIPT_OFF  65536    // w_ih same layout                                            (128*512)
#define PP_OFF    131072   // P'' = w_emb@w_ih^T + bsum, layout [j][4*hh+q]               (8*512)
#define BSUM_OFF  135168   // (b_ih+b_hh) permuted [q*128+hh]                             (512)

__global__ __launch_bounds__(256) void setup_kernel(
    const float* __restrict__ w_emb, const float* __restrict__ w_ih,
    const float* __restrict__ w_hh, const float* __restrict__ b_ih,
    const float* __restrict__ b_hh, float* __restrict__ ws)
{
  int tid = blockIdx.x * blockDim.x + threadIdx.x;
  if (tid < 65536) {
    int k = tid >> 9, col = tid & 511;
    int hh = col >> 2, q = col & 3;
    ws[WPT_OFF + tid]  = w_hh[(q*HD + hh)*HD + k];
    ws[WIPT_OFF + tid] = w_ih[(q*HD + hh)*HD + k];
  }
  if (tid < 4096) {
    int j = tid >> 9, rem = tid & 511;
    int q = rem >> 7, hh2 = rem & 127;
    const float* wr = w_ih + (q*HD + hh2)*HD;
    const float* er = w_emb + j*HD;
    float s = 0.f;
    for (int k = 0; k < HD; ++k) s = fmaf(er[k], wr[k], s);
    ws[PP_OFF + (size_t)j*512 + 4*hh2 + q] = s + b_ih[q*HD + hh2] + b_hh[q*HD + hh2];
  }
  if (tid < 512) {
    int q = tid >> 7, hh2 = tid & 127;
    ws[BSUM_OFF + tid] = b_ih[q*HD + hh2] + b_hh[q*HD + hh2];
  }
}

__device__ __forceinline__ float fsig(float x) {
  return __fdividef(1.f, 1.f + __expf(-x));
}
__device__ __forceinline__ float ftanh(float x) {
  float ax = fabsf(x);
  float e  = __expf(-2.f * ax);
  float r  = __fdividef(1.f - e, 1.f + e);
  return copysignf(r, x);
}

// 32 explicit-component FMAs for one k (no arrays -> no unpack movs)
#define ROWQ(qi, wq, HA, HB) \
  acc[qi][0] = fmaf((HA).x, wq, acc[qi][0]); acc[qi][1] = fmaf((HA).y, wq, acc[qi][1]); \
  acc[qi][2] = fmaf((HA).z, wq, acc[qi][2]); acc[qi][3] = fmaf((HA).w, wq, acc[qi][3]); \
  acc[qi][4] = fmaf((HB).x, wq, acc[qi][4]); acc[qi][5] = fmaf((HB).y, wq, acc[qi][5]); \
  acc[qi][6] = fmaf((HB).z, wq, acc[qi][6]); acc[qi][7] = fmaf((HB).w, wq, acc[qi][7]);

#define KFMA(W, HA, HB) \
  ROWQ(0, (W).x, HA, HB) ROWQ(1, (W).y, HA, HB) ROWQ(2, (W).z, HA, HB) ROWQ(3, (W).w, HA, HB)

// lgkm-only barrier: no vmcnt(0) drain (out-stores / prefetches stay in flight)
#define BAR_LGKM() asm volatile("s_waitcnt lgkmcnt(0)\n\ts_barrier" ::: "memory")

__global__ __launch_bounds__(512, 4) void ctrl_kernel(
    const int* __restrict__ class_ids,
    const float* __restrict__ gumbel_u,
    const float* __restrict__ g_emb,
    const float* __restrict__ w_soft,
    const float* __restrict__ ws,
    float* __restrict__ out,
    int Btot)
{
  __shared__ __align__(16) float hT0[HD * HT_PAD];          // 18432 B
  __shared__ __align__(16) float hT1[HD * HT_PAD];          // 18432 B
  __shared__ __align__(16) float wsoft_l[NBR * HD];         // 4096 B
  __shared__ __align__(16) float part_l[TILE_B * PART_PAD]; // 16896 B
  __shared__ __align__(16) float pp_l[NBR * 512];           // 16384 B
  __shared__ int br_l[TILE_B];                              // 128 B  (~74.4 KB -> 2 blocks/CU)

  const int tid = threadIdx.x;
  const int b0  = blockIdx.x * TILE_B;
  const size_t BL = (size_t)Btot * LSTEPS;

  const float* __restrict__ wpT  = ws + WPT_OFF;
  const float* __restrict__ wipT = ws + WIPT_OFF;

  for (int i = tid; i < NBR*HD; i += 512) wsoft_l[i] = w_soft[i];
  for (int i = tid; i < NBR*512; i += 512) pp_l[i] = ws[PP_OFF + i];

  const int hh = tid & 127;   // hidden index
  const int bg = tid >> 7;    // batch group 0..3 (8 batches each)
  const int slb = tid >> 4;   // sampling: batch owned by this 16-lane group
  const int sr  = tid & 15;   // sampling: lane within group

  // ---- stage x0^T = g_emb[class_ids]^T into hT0 ----
  {
    int sb = tid >> 4;
    int kc = tid & 15;
    int cid = class_ids[b0 + sb];
    const float* src = g_emb + (size_t)cid * HD + kc*8;
    float4 v0 = *(const float4*)(src);
    float4 v1 = *(const float4*)(src + 4);
    int kb = kc*8;
    hT0[(kb+0)*HT_PAD + sb] = v0.x;
    hT0[(kb+1)*HT_PAD + sb] = v0.y;
    hT0[(kb+2)*HT_PAD + sb] = v0.z;
    hT0[(kb+3)*HT_PAD + sb] = v0.w;
    hT0[(kb+4)*HT_PAD + sb] = v1.x;
    hT0[(kb+5)*HT_PAD + sb] = v1.y;
    hT0[(kb+6)*HT_PAD + sb] = v1.z;
    hT0[(kb+7)*HT_PAD + sb] = v1.w;
  }
  __syncthreads();

  // ---- q0h = 0.5*(x0 @ w_ih^T + bsum), parked in 32 AGPRs ----
  float qpark[32];
  {
    float acc[4][8];
    #pragma unroll
    for (int q = 0; q < 4; ++q)
      #pragma unroll
      for (int j = 0; j < 8; ++j) acc[q][j] = 0.f;

    const float* wr = wipT + 4*hh;
    const float* hr = hT0 + bg*8;
    #pragma unroll 2
    for (int k = 0; k < HD; ++k) {
      float4 w  = *(const float4*)(wr);
      float4 ha = *(const float4*)(hr);
      float4 hb = *(const float4*)(hr + 4);
      KFMA(w, ha, hb);
      wr += 512; hr += HT_PAD;
    }
    #pragma unroll
    for (int q = 0; q < 4; ++q) {
      float bs = ws[BSUM_OFF + q*HD + hh];
      #pragma unroll
      for (int j = 0; j < 8; ++j) {
        float v = 0.5f * (acc[q][j] + bs);
        asm("v_accvgpr_write_b32 %0, %1" : "=a"(qpark[q*8+j]) : "v"(v));
      }
    }
  }
  __syncthreads();

  float c[8];
  #pragma unroll
  for (int j = 0; j < 8; ++j) c[j] = 0.f;

  float* hcur = hT0;
  float* hnxt = hT1;

  for (int t = 0; t < LSTEPS; ++t) {
    // ---- gumbel load + transform, only in the finalize-owner lanes (overlaps GEMM) ----
    float gmb[8];
    if (sr == 0) {
      const float* up = gumbel_u + ((size_t)t * Btot + (b0 + slb)) * NBR;
      float4 ua = *(const float4*)up;
      float4 ub = *(const float4*)(up + 4);
      float uv[8] = {ua.x,ua.y,ua.z,ua.w,ub.x,ub.y,ub.z,ub.w};
      #pragma unroll
      for (int nb = 0; nb < 8; ++nb) {
        float uc = fminf(fmaxf(uv[nb], 1e-8f), 0.99999999f);
        gmb[nb] = -__logf(-__logf(uc));
      }
    }

    // ---- acc starts at parked q0h; GEMM adds h @ w_hh^T (2-k-deep software pipeline) ----
    float acc[4][8];
    #pragma unroll
    for (int q = 0; q < 4; ++q)
      #pragma unroll
      for (int j = 0; j < 8; ++j)
        asm("v_accvgpr_read_b32 %0, %1" : "=v"(acc[q][j]) : "a"(qpark[q*8+j]));

    if (t > 0) {
      __builtin_amdgcn_s_setprio(1);
      const float* wr = wpT + 4*hh;
      const float* hr = hcur + bg*8;
      // prologue: k=0,1 in flight
      float4 w0 = *(const float4*)(wr);
      float4 w1 = *(const float4*)(wr + 512);
      float4 a0 = *(const float4*)(hr);
      float4 b0v = *(const float4*)(hr + 4);
      float4 a1 = *(const float4*)(hr + HT_PAD);
      float4 b1 = *(const float4*)(hr + HT_PAD + 4);
      #pragma unroll 3
      for (int kb = 0; kb < 63; ++kb) {
        // consume k=2kb, prefetch k=2kb+2 (dep distance = 2k = 256 issue-cyc > L2 latency)
        float4 wc = w0, ac = a0, bc = b0v;
        w0  = *(const float4*)(wr + 2*512);
        a0  = *(const float4*)(hr + 2*HT_PAD);
        b0v = *(const float4*)(hr + 2*HT_PAD + 4);
        KFMA(wc, ac, bc);
        // consume k=2kb+1, prefetch k=2kb+3
        float4 wd = w1, ad = a1, bd = b1;
        w1 = *(const float4*)(wr + 3*512);
        a1 = *(const float4*)(hr + 3*HT_PAD);
        b1 = *(const float4*)(hr + 3*HT_PAD + 4);
        KFMA(wd, ad, bd);
        wr += 1024; hr += 2*HT_PAD;
      }
      // epilogue: k=126,127 (no prefetch issued beyond k=127 -> no OOB)
      KFMA(w0, a0, b0v);
      KFMA(w1, a1, b1);
      __builtin_amdgcn_s_setprio(0);
    }

    // ---- combine x-part, LSTM pointwise ----
    float h2v[8];
    #pragma unroll
    for (int j = 0; j < 8; ++j) {
      float gi, gf, gg, go;
      if (t == 0) {
        gi = 2.f*acc[0][j]; gf = 2.f*acc[1][j];
        gg = 2.f*acc[2][j]; go = 2.f*acc[3][j];
      } else {
        int br = br_l[bg*8 + j];
        float4 pv = *(const float4*)(&pp_l[br*512 + 4*hh]);
        gi = fmaf(0.5f, pv.x, acc[0][j]);
        gf = fmaf(0.5f, pv.y, acc[1][j]);
        gg = fmaf(0.5f, pv.z, acc[2][j]);
        go = fmaf(0.5f, pv.w, acc[3][j]);
      }
      float iv = fsig(gi);
      float fv = fsig(gf);
      float gv = ftanh(gg);
      float ov = fsig(go);
      float c2 = fmaf(fv, c[j], iv*gv);
      c[j] = c2;
      h2v[j] = ov * ftanh(c2);
    }

    // write h_{t+1} into the other buffer (no pre-write barrier needed)
    {
      float* dst = &hnxt[hh*HT_PAD + bg*8];
      *(float4*)(dst)   = make_float4(h2v[0],h2v[1],h2v[2],h2v[3]);
      *(float4*)(dst+4) = make_float4(h2v[4],h2v[5],h2v[6],h2v[7]);
    }
    BAR_LGKM();   // (B) new h visible (LDS only)

    // ---- logit partials: thread (lb = tid&31, ch = tid>>5), 8-k chunk each ----
    {
      int lb = tid & 31, ch = tid >> 5;
      const float* hp = hnxt + (ch*8)*HT_PAD + lb;
      float hv[8];
      #pragma unroll
      for (int i = 0; i < 8; ++i) hv[i] = hp[i*HT_PAD];
      #pragma unroll
      for (int nb = 0; nb < 8; ++nb) {
        const float4* wr2 = (const float4*)&wsoft_l[nb*HD + ch*8];
        float4 wa = wr2[0], wb = wr2[1];
        float p = 0.f;
        p = fmaf(hv[0], wa.x, p); p = fmaf(hv[1], wa.y, p);
        p = fmaf(hv[2], wa.z, p); p = fmaf(hv[3], wa.w, p);
        p = fmaf(hv[4], wb.x, p); p = fmaf(hv[5], wb.y, p);
        p = fmaf(hv[6], wb.z, p); p = fmaf(hv[7], wb.w, p);
        part_l[lb*PART_PAD + nb*16 + ch] = p;
      }
    }
    BAR_LGKM();   // (C) partials visible

    // ---- sampling: 16-lane group per batch, butterfly reduce, lane 0 finalizes ----
    {
      float s[8];
      #pragma unroll
      for (int nb = 0; nb < 8; ++nb)
        s[nb] = part_l[slb*PART_PAD + nb*16 + sr];
      #pragma unroll
      for (int mk = 1; mk < 16; mk <<= 1) {
        #pragma unroll
        for (int nb = 0; nb < 8; ++nb)
          s[nb] += __shfl_xor(s[nb], mk, 64);   // masks 1,2,4,8 stay within the 16-group
      }
      if (sr == 0) {
        float lg[8];
        #pragma unroll
        for (int nb = 0; nb < 8; ++nb)
          lg[nb] = 2.5f * ftanh(s[nb] * 0.2f);
        int br = 0; float best = lg[0] + gmb[0];
        #pragma unroll
        for (int nb = 1; nb < 8; ++nb) {
          float y = lg[nb] + gmb[nb];
          if (y > best) { best = y; br = nb; }   // strict > == first-occurrence argmax
        }
        br_l[slb] = br;
        float m = lg[0];
        #pragma unroll
        for (int nb = 1; nb < 8; ++nb) m = fmaxf(m, lg[nb]);
        float se = 0.f;
        #pragma unroll
        for (int nb = 0; nb < 8; ++nb) se += __expf(lg[nb] - m);
        float lse = __logf(se);
        float lp = (lg[br] - m) - lse;
        float ent = 0.f;
        #pragma unroll
        for (int nb = 0; nb < 8; ++nb) {
          float lpi = (lg[nb] - m) - lse;
          ent -= __expf(lpi) * lpi;
        }
        size_t row = (size_t)(b0 + slb) * LSTEPS + t;
        out[row]        = (float)br;
        out[BL + row]   = lp;
        out[2*BL + row] = ent;
        out[3*BL + row] = __expf(lp);
      }
    }
    BAR_LGKM();   // (E) br_l visible for next step's combine

    float* tmp = hcur; hcur = hnxt; hnxt = tmp;
  }
}

extern "C" void kernel_launch(void* const* d_in, const int* in_sizes, int n_in,
                              void* d_out, int out_size, void* d_ws, size_t ws_size,
                              hipStream_t stream) {
  const int*   class_ids = (const int*)d_in[0];
  const float* gumbel_u  = (const float*)d_in[1];
  const float* g_emb     = (const float*)d_in[2];
  const float* w_emb     = (const float*)d_in[3];
  const float* w_soft    = (const float*)d_in[4];
  const float* w_ih      = (const float*)d_in[5];
  const float* w_hh      = (const float*)d_in[6];
  const float* b_ih      = (const float*)d_in[7];
  const float* b_hh      = (const float*)d_in[8];
  float* out = (float*)d_out;
  float* ws  = (float*)d_ws;
  int B = in_sizes[0];

  hipLaunchKernelGGL(setup_kernel, dim3(256), dim3(256), 0, stream,
                     w_emb, w_ih, w_hh, b_ih, b_hh, ws);
  hipLaunchKernelGGL(ctrl_kernel, dim3(B / TILE_B), dim3(512), 0, stream,
                     class_ids, gumbel_u, g_emb, w_soft, ws, out, B);
}